// Round 2
// baseline (2412.340 us; speedup 1.0000x reference)
//
#include <hip/hip_runtime.h>

#define D 128
#define TPB 512   // 8 waves; 64KB LDS -> 2 blocks/CU -> 4 waves/SIMD

// ---------------- preprocessing: CSR permutation ----------------

__global__ void hist_kernel(const int* __restrict__ assign, int n, int* __restrict__ cnt) {
    int i = blockIdx.x * blockDim.x + threadIdx.x;
    if (i < n) atomicAdd(&cnt[assign[i]], 1);
}

// exclusive scan of cnt[0..n) into head[0..n). single block, 1024 threads.
__global__ void scan_kernel(const int* __restrict__ cnt, int n, int* __restrict__ head) {
    __shared__ int part[1024];
    const int t = threadIdx.x;
    const int per = (n + 1023) >> 10;
    const int lo = t * per;
    const int hi = min(lo + per, n);
    int s = 0;
    for (int i = lo; i < hi; ++i) s += cnt[i];
    part[t] = s;
    __syncthreads();
    for (int d = 1; d < 1024; d <<= 1) {
        int v = (t >= d) ? part[t - d] : 0;
        __syncthreads();
        part[t] += v;
        __syncthreads();
    }
    int base = (t > 0) ? part[t - 1] : 0;
    for (int i = lo; i < hi; ++i) { head[i] = base; base += cnt[i]; }
}

// perm[pos] = row, rows grouped by segment (order within segment arbitrary)
__global__ void perm_kernel(const int* __restrict__ assign, int n,
                            int* __restrict__ head, int* __restrict__ perm) {
    int i = blockIdx.x * blockDim.x + threadIdx.x;
    if (i < n) {
        int p = atomicAdd(&head[assign[i]], 1);
        perm[p] = i;
    }
}

// ---------------- K1/K3: MLP (relu(x@W^T+b)) + run-combined scatter-sum ----------------
// Rows processed in perm (segment-sorted) order. Wave owns 16 consecutive
// positions; lane owns cols {lane, lane+64}. Consecutive rows mostly share a
// segment -> combine in registers, flush with atomics only at boundaries.
__global__ __launch_bounds__(TPB, 4)
void mlp_scatter(const float* __restrict__ X,
                 const float* __restrict__ W,
                 const float* __restrict__ bias,
                 const int*   __restrict__ perm,
                 const int*   __restrict__ assign,
                 float* __restrict__ Out,
                 int nrows, int ntiles)
{
    __shared__ float Wt[D * D];  // Wt[k*D + c] = W[c*D + k]
    const int t    = threadIdx.x;
    const int lane = t & 63;
    const int wid  = __builtin_amdgcn_readfirstlane(t >> 6);  // 0..7

    #pragma unroll
    for (int u = 0; u < 8; ++u) {            // 512 thr * float4 * 8 = 16384
        int flat = u * 2048 + t * 4;
        int c = flat >> 7, k = flat & 127;
        float4 wv = *(const float4*)(W + flat);
        Wt[(k + 0) * D + c] = wv.x;
        Wt[(k + 1) * D + c] = wv.y;
        Wt[(k + 2) * D + c] = wv.z;
        Wt[(k + 3) * D + c] = wv.w;
    }
    const float b0 = bias[lane];
    const float b1 = bias[lane + 64];
    __syncthreads();

    for (int tile = blockIdx.x; tile < ntiles; tile += gridDim.x) {
        const int p0 = tile * 128 + wid * 16;
        if (p0 >= nrows) continue;

        // wave-uniform row/segment metadata (SGPRs)
        const float* xb[16];
        int segv[16];
        #pragma unroll
        for (int r = 0; r < 16; ++r) {
            int p = p0 + r; if (p >= nrows) p = nrows - 1;
            int row = __builtin_amdgcn_readfirstlane(perm[p]);
            xb[r]   = X + (size_t)row * D;
            segv[r] = __builtin_amdgcn_readfirstlane(assign[row]);
        }

        float acc0[16], acc1[16];
        #pragma unroll
        for (int r = 0; r < 16; ++r) { acc0[r] = 0.f; acc1[r] = 0.f; }

        #pragma unroll 4
        for (int k = 0; k < D; ++k) {
            float w0 = Wt[k * D + lane];
            float w1 = Wt[k * D + lane + 64];
            #pragma unroll
            for (int r = 0; r < 16; ++r) {
                float x = xb[r][k];
                acc0[r] = fmaf(x, w0, acc0[r]);
                acc1[r] = fmaf(x, w1, acc1[r]);
            }
        }

        // epilogue: bias+relu, combine runs of equal segment, flush at boundaries
        float s0 = 0.f, s1 = 0.f;
        int cur = segv[0];
        #pragma unroll
        for (int r = 0; r < 16; ++r) {
            if (p0 + r >= nrows) break;
            float y0 = fmaxf(acc0[r] + b0, 0.f);
            float y1 = fmaxf(acc1[r] + b1, 0.f);
            if (segv[r] != cur) {
                float* o = Out + (size_t)cur * D;
                unsafeAtomicAdd(o + lane,      s0);
                unsafeAtomicAdd(o + lane + 64, s1);
                cur = segv[r]; s0 = 0.f; s1 = 0.f;
            }
            s0 += y0; s1 += y1;
        }
        float* o = Out + (size_t)cur * D;
        unsafeAtomicAdd(o + lane,      s0);
        unsafeAtomicAdd(o + lane + 64, s1);
    }
}

// ---------------- K2/K4: dense y = (Xsum/cnt)@W^T + b (in place safe) ----------------
__global__ __launch_bounds__(TPB, 4)
void dense_lin(const float* __restrict__ Xin,
               const float* __restrict__ W,
               const float* __restrict__ bias,
               const int*   __restrict__ cnt_in,
               float* __restrict__ Out,
               int nrows, int ntiles)
{
    __shared__ float Wt[D * D];
    const int t    = threadIdx.x;
    const int lane = t & 63;
    const int wid  = __builtin_amdgcn_readfirstlane(t >> 6);

    #pragma unroll
    for (int u = 0; u < 8; ++u) {
        int flat = u * 2048 + t * 4;
        int c = flat >> 7, k = flat & 127;
        float4 wv = *(const float4*)(W + flat);
        Wt[(k + 0) * D + c] = wv.x;
        Wt[(k + 1) * D + c] = wv.y;
        Wt[(k + 2) * D + c] = wv.z;
        Wt[(k + 3) * D + c] = wv.w;
    }
    const float b0 = bias[lane];
    const float b1 = bias[lane + 64];
    __syncthreads();

    for (int tile = blockIdx.x; tile < ntiles; tile += gridDim.x) {
        const int r0 = tile * 128 + wid * 16;
        if (r0 >= nrows) continue;

        float acc0[16], acc1[16];
        #pragma unroll
        for (int r = 0; r < 16; ++r) { acc0[r] = 0.f; acc1[r] = 0.f; }

        if (r0 + 16 <= nrows) {
            const float* xb = Xin + (size_t)r0 * D;
            #pragma unroll 4
            for (int k = 0; k < D; ++k) {
                float w0 = Wt[k * D + lane];
                float w1 = Wt[k * D + lane + 64];
                #pragma unroll
                for (int r = 0; r < 16; ++r) {
                    float x = xb[r * D + k];
                    acc0[r] = fmaf(x, w0, acc0[r]);
                    acc1[r] = fmaf(x, w1, acc1[r]);
                }
            }
        } else {
            #pragma unroll 2
            for (int k = 0; k < D; ++k) {
                float w0 = Wt[k * D + lane];
                float w1 = Wt[k * D + lane + 64];
                #pragma unroll
                for (int r = 0; r < 16; ++r) {
                    int rr = (r0 + r < nrows) ? (r0 + r) : (nrows - 1);
                    float x = Xin[(size_t)rr * D + k];
                    acc0[r] = fmaf(x, w0, acc0[r]);
                    acc1[r] = fmaf(x, w1, acc1[r]);
                }
            }
        }

        #pragma unroll
        for (int r = 0; r < 16; ++r) {
            int row = r0 + r;
            if (row >= nrows) break;
            int   c = cnt_in[row];
            float s = (c > 0) ? (1.f / (float)c) : 0.f;
            float y0 = acc0[r] * s + ((c > 0) ? b0 : 0.f);
            float y1 = acc1[r] * s + ((c > 0) ? b1 : 0.f);
            float* o = Out + (size_t)row * D;
            o[lane]      = y0;
            o[lane + 64] = y1;
        }
    }
}

extern "C" void kernel_launch(void* const* d_in, const int* in_sizes, int n_in,
                              void* d_out, int out_size, void* d_ws, size_t ws_size,
                              hipStream_t stream) {
    const float* x_building = (const float*)d_in[0];   // 1048576 x 128
    const int*   assign_bc  = (const int*)  d_in[1];   // 1048576
    const int*   assign_ct  = (const int*)  d_in[2];   // 50000
    const float* w1 = (const float*)d_in[3];
    const float* b1 = (const float*)d_in[4];
    const float* w2 = (const float*)d_in[5];
    const float* b2 = (const float*)d_in[6];
    const float* w3 = (const float*)d_in[7];
    const float* b3 = (const float*)d_in[8];
    const float* w4 = (const float*)d_in[9];
    const float* b4 = (const float*)d_in[10];

    const int N_BUILD = 1048576;
    const int N_CABLE = 50000;
    const int N_TRANS = 2000;

    float* out = (float*)d_out;
    float* S_c = out;                       // 50000 x 128 (x_cable slot)
    float* S_t = out + (size_t)N_CABLE * D; // 2000 x 128 (x_trans slot)

    // workspace layout (ints), ~4.8 MB total
    int* ws      = (int*)d_ws;
    int* cnt_c   = ws;                      // 50000
    int* cnt_t   = cnt_c + N_CABLE;         // 2000
    int* head_c  = cnt_t + N_TRANS;         // 50000
    int* head_t  = head_c + N_CABLE;        // 2000
    int* perm_c  = head_t + N_TRANS;        // 1048576
    int* perm_t  = perm_c + N_BUILD;        // 50000

    // zero the accumulators (harness poisons d_out/d_ws with 0xAA)
    hipMemsetAsync(d_out, 0, (size_t)out_size * sizeof(float), stream);
    hipMemsetAsync(cnt_c, 0, (size_t)(N_CABLE + N_TRANS) * sizeof(int), stream);

    // CSR permutations for both levels
    hist_kernel<<<(N_BUILD + 255) / 256, 256, 0, stream>>>(assign_bc, N_BUILD, cnt_c);
    hist_kernel<<<(N_CABLE + 255) / 256, 256, 0, stream>>>(assign_ct, N_CABLE, cnt_t);
    scan_kernel<<<1, 1024, 0, stream>>>(cnt_c, N_CABLE, head_c);
    scan_kernel<<<1, 1024, 0, stream>>>(cnt_t, N_TRANS, head_t);
    perm_kernel<<<(N_BUILD + 255) / 256, 256, 0, stream>>>(assign_bc, N_BUILD, head_c, perm_c);
    perm_kernel<<<(N_CABLE + 255) / 256, 256, 0, stream>>>(assign_ct, N_CABLE, head_t, perm_t);

    // K1: scatter-sum relu(X@W1^T+b1) into S_c, segment-sorted order
    {
        int ntiles = N_BUILD / 128;  // 8192 exact
        mlp_scatter<<<512, TPB, 0, stream>>>(
            x_building, w1, b1, perm_c, assign_bc, S_c, N_BUILD, ntiles);
    }
    // K2: x_cable = (S_c/cnt)@W2^T + b2, in place
    {
        int ntiles = (N_CABLE + 127) / 128;  // 391
        dense_lin<<<391, TPB, 0, stream>>>(
            S_c, w2, b2, cnt_c, S_c, N_CABLE, ntiles);
    }
    // K3: scatter-sum relu(x_cable@W3^T+b3) into S_t
    {
        int ntiles = (N_CABLE + 127) / 128;
        mlp_scatter<<<391, TPB, 0, stream>>>(
            S_c, w3, b3, perm_t, assign_ct, S_t, N_CABLE, ntiles);
    }
    // K4: x_trans = (S_t/cnt)@W4^T + b4, in place
    {
        int ntiles = (N_TRANS + 127) / 128;  // 16
        dense_lin<<<16, TPB, 0, stream>>>(
            S_t, w4, b4, cnt_t, S_t, N_TRANS, ntiles);
    }
}

// Round 3
// 1632.489 us; speedup vs baseline: 1.4777x; 1.4777x over previous
//
#include <hip/hip_runtime.h>

#define D 128

// ---------------- preprocessing ----------------

__global__ void hist_kernel(const int* __restrict__ assign, int n, int* __restrict__ cnt) {
    int i = blockIdx.x * blockDim.x + threadIdx.x;
    if (i < n) atomicAdd(&cnt[assign[i]], 1);
}

// exclusive scan of cnt[0..n) into head[0..n). single block, 1024 threads.
__global__ void scan_kernel(const int* __restrict__ cnt, int n, int* __restrict__ head) {
    __shared__ int part[1024];
    const int t = threadIdx.x;
    const int per = (n + 1023) >> 10;
    const int lo = t * per;
    const int hi = min(lo + per, n);
    int s = 0;
    for (int i = lo; i < hi; ++i) s += cnt[i];
    part[t] = s;
    __syncthreads();
    for (int d = 1; d < 1024; d <<= 1) {
        int v = (t >= d) ? part[t - d] : 0;
        __syncthreads();
        part[t] += v;
        __syncthreads();
    }
    int base = (t > 0) ? part[t - 1] : 0;
    for (int i = lo; i < hi; ++i) { head[i] = base; base += cnt[i]; }
}

__global__ void perm_kernel(const int* __restrict__ assign, int n,
                            int* __restrict__ head, int* __restrict__ perm) {
    int i = blockIdx.x * blockDim.x + threadIdx.x;
    if (i < n) {
        int p = atomicAdd(&head[assign[i]], 1);
        perm[p] = i;
    }
}

// Wt[k*128 + c] = W[c*128 + k]
__global__ void transpose_w(const float* __restrict__ W, float* __restrict__ Wt) {
    int g = blockIdx.x * 256 + threadIdx.x;   // 0..16383
    int k = g >> 7, c = g & 127;
    Wt[g] = W[c * D + k];
}

// ---------------- unified 128x128 register-blocked GEMM ----------------
// Block: 256 threads = 16x16 grid (tx,ty); thread owns 8 rows x 8 cols.
// Tile: 128 rows (perm-ordered if PERM) x 128 cols. K staged in chunks of 32.
// Xs is k-major ([k][r]) so A-frag reads are ds_read_b128 broadcasts.
// No scalar loads in the hot loop (the round-2 bottleneck: s_load -> lgkmcnt(0) drains).
template<bool PERM, bool SCATTER, bool RELU, bool SCALE>
__global__ __launch_bounds__(256, 3)
void gemm128(const float* __restrict__ X,
             const float* __restrict__ Wt,     // pre-transposed [k][c]
             const float* __restrict__ bias,
             const int*   __restrict__ perm,
             const int*   __restrict__ assign,
             const int*   __restrict__ cnt_in,
             float* __restrict__ Out,
             int nrows)
{
    __shared__ float Xs[32 * D];   // [k][r]
    __shared__ float Ws[32 * D];   // [k][c]
    __shared__ int   rowmap[128];
    __shared__ int   segs[128];

    const int t  = threadIdx.x;
    const int tx = t & 15;
    const int ty = t >> 4;
    const int p0 = blockIdx.x * 128;

    if (t < 128) {
        int p  = p0 + t;
        int pc = (p < nrows) ? p : (nrows - 1);
        int row = PERM ? perm[pc] : pc;
        rowmap[t] = row;
        if (SCATTER) segs[t] = assign[row];
    }
    __syncthreads();

    // staging identity: thread covers 16 k-values (one 64B chunk) of one row
    const int sr    = t >> 1;            // row 0..127
    const int schnk = (t & 1) * 16;      // k offset 0 or 16
    const float* xrow = X + (size_t)rowmap[sr] * D + schnk;

    const int wk = t >> 3;               // 0..31
    const int wc = (t & 7) * 16;
    const float* wbase = Wt + (size_t)wk * D + wc;

    float bb[8];
    #pragma unroll
    for (int j = 0; j < 8; ++j) bb[j] = bias[tx * 8 + j];

    float acc[8][8];
    #pragma unroll
    for (int i = 0; i < 8; ++i)
        #pragma unroll
        for (int j = 0; j < 8; ++j) acc[i][j] = 0.f;

    for (int ks = 0; ks < D; ks += 32) {
        // global loads (vmcnt path; overlap previous stage's compute)
        float4 xv0 = *(const float4*)(xrow + ks + 0);
        float4 xv1 = *(const float4*)(xrow + ks + 4);
        float4 xv2 = *(const float4*)(xrow + ks + 8);
        float4 xv3 = *(const float4*)(xrow + ks + 12);
        const float* wrow = wbase + (size_t)ks * D;
        float4 wv0 = *(const float4*)(wrow + 0);
        float4 wv1 = *(const float4*)(wrow + 4);
        float4 wv2 = *(const float4*)(wrow + 8);
        float4 wv3 = *(const float4*)(wrow + 12);

        __syncthreads();   // previous stage's compute done before overwrite

        // Xs transpose-store: bank = sr%32, 2-way (free)
        Xs[(schnk +  0) * D + sr] = xv0.x;
        Xs[(schnk +  1) * D + sr] = xv0.y;
        Xs[(schnk +  2) * D + sr] = xv0.z;
        Xs[(schnk +  3) * D + sr] = xv0.w;
        Xs[(schnk +  4) * D + sr] = xv1.x;
        Xs[(schnk +  5) * D + sr] = xv1.y;
        Xs[(schnk +  6) * D + sr] = xv1.z;
        Xs[(schnk +  7) * D + sr] = xv1.w;
        Xs[(schnk +  8) * D + sr] = xv2.x;
        Xs[(schnk +  9) * D + sr] = xv2.y;
        Xs[(schnk + 10) * D + sr] = xv2.z;
        Xs[(schnk + 11) * D + sr] = xv2.w;
        Xs[(schnk + 12) * D + sr] = xv3.x;
        Xs[(schnk + 13) * D + sr] = xv3.y;
        Xs[(schnk + 14) * D + sr] = xv3.z;
        Xs[(schnk + 15) * D + sr] = xv3.w;
        // Ws contiguous store
        *(float4*)(Ws + wk * D + wc +  0) = wv0;
        *(float4*)(Ws + wk * D + wc +  4) = wv1;
        *(float4*)(Ws + wk * D + wc +  8) = wv2;
        *(float4*)(Ws + wk * D + wc + 12) = wv3;

        __syncthreads();

        #pragma unroll
        for (int k = 0; k < 32; ++k) {
            float a[8], b[8];
            *(float4*)(a + 0) = *(const float4*)(Xs + k * D + ty * 8 + 0);
            *(float4*)(a + 4) = *(const float4*)(Xs + k * D + ty * 8 + 4);
            *(float4*)(b + 0) = *(const float4*)(Ws + k * D + tx * 8 + 0);
            *(float4*)(b + 4) = *(const float4*)(Ws + k * D + tx * 8 + 4);
            #pragma unroll
            for (int i = 0; i < 8; ++i)
                #pragma unroll
                for (int j = 0; j < 8; ++j)
                    acc[i][j] = fmaf(a[i], b[j], acc[i][j]);
        }
    }

    if (!SCATTER) {
        #pragma unroll
        for (int i = 0; i < 8; ++i) {
            int row = p0 + ty * 8 + i;
            if (row < nrows) {
                float s = 1.f;
                bool nz = true;
                if (SCALE) {
                    int c = cnt_in[row];
                    nz = (c > 0);
                    s  = nz ? (1.f / (float)c) : 0.f;
                }
                float y[8];
                #pragma unroll
                for (int j = 0; j < 8; ++j) {
                    y[j] = acc[i][j] * s + (nz ? bb[j] : 0.f);
                    if (RELU) y[j] = fmaxf(y[j], 0.f);
                }
                float* o = Out + (size_t)row * D + tx * 8;
                *(float4*)(o + 0) = *(const float4*)(y + 0);
                *(float4*)(o + 4) = *(const float4*)(y + 4);
            }
        }
    } else {
        // run-combined scatter: rows are segment-sorted (perm order)
        float s[8];
        #pragma unroll
        for (int j = 0; j < 8; ++j) s[j] = 0.f;
        int cur = segs[ty * 8];
        #pragma unroll
        for (int i = 0; i < 8; ++i) {
            int p  = p0 + ty * 8 + i;
            int sg = segs[ty * 8 + i];
            float m = (p < nrows) ? 1.f : 0.f;
            if (sg != cur) {
                float* o = Out + (size_t)cur * D + tx * 8;
                #pragma unroll
                for (int j = 0; j < 8; ++j) unsafeAtomicAdd(o + j, s[j]);
                cur = sg;
                #pragma unroll
                for (int j = 0; j < 8; ++j) s[j] = 0.f;
            }
            #pragma unroll
            for (int j = 0; j < 8; ++j) {
                float y = acc[i][j] + bb[j];
                if (RELU) y = fmaxf(y, 0.f);
                s[j] += m * y;
            }
        }
        float* o = Out + (size_t)cur * D + tx * 8;
        #pragma unroll
        for (int j = 0; j < 8; ++j) unsafeAtomicAdd(o + j, s[j]);
    }
}

extern "C" void kernel_launch(void* const* d_in, const int* in_sizes, int n_in,
                              void* d_out, int out_size, void* d_ws, size_t ws_size,
                              hipStream_t stream) {
    const float* x_building = (const float*)d_in[0];   // 1048576 x 128
    const int*   assign_bc  = (const int*)  d_in[1];   // 1048576
    const int*   assign_ct  = (const int*)  d_in[2];   // 50000
    const float* w1 = (const float*)d_in[3];
    const float* b1 = (const float*)d_in[4];
    const float* w2 = (const float*)d_in[5];
    const float* b2 = (const float*)d_in[6];
    const float* w3 = (const float*)d_in[7];
    const float* b3 = (const float*)d_in[8];
    const float* w4 = (const float*)d_in[9];
    const float* b4 = (const float*)d_in[10];

    const int N_BUILD = 1048576;
    const int N_CABLE = 50000;
    const int N_TRANS = 2000;

    float* out = (float*)d_out;
    float* S_c = out;                        // 50000 x 128
    float* S_t = out + (size_t)N_CABLE * D;  // 2000 x 128

    // workspace layout
    int* ws     = (int*)d_ws;
    int* cnt_c  = ws;                        // 50000
    int* cnt_t  = cnt_c + N_CABLE;           // 2000
    int* head_c = cnt_t + N_TRANS;           // 50000
    int* head_t = head_c + N_CABLE;          // 2000
    int* perm_c = head_t + N_TRANS;          // 1048576
    int* perm_t = perm_c + N_BUILD;          // 50000
    float* Wt1  = (float*)(perm_t + N_CABLE);
    float* Wt2  = Wt1 + D * D;
    float* Wt3  = Wt2 + D * D;
    float* Wt4  = Wt3 + D * D;

    hipMemsetAsync(d_out, 0, (size_t)out_size * sizeof(float), stream);
    hipMemsetAsync(cnt_c, 0, (size_t)(N_CABLE + N_TRANS) * sizeof(int), stream);

    // preprocessing: CSR perms + weight transposes
    hist_kernel<<<(N_BUILD + 255) / 256, 256, 0, stream>>>(assign_bc, N_BUILD, cnt_c);
    hist_kernel<<<(N_CABLE + 255) / 256, 256, 0, stream>>>(assign_ct, N_CABLE, cnt_t);
    scan_kernel<<<1, 1024, 0, stream>>>(cnt_c, N_CABLE, head_c);
    scan_kernel<<<1, 1024, 0, stream>>>(cnt_t, N_TRANS, head_t);
    perm_kernel<<<(N_BUILD + 255) / 256, 256, 0, stream>>>(assign_bc, N_BUILD, head_c, perm_c);
    perm_kernel<<<(N_CABLE + 255) / 256, 256, 0, stream>>>(assign_ct, N_CABLE, head_t, perm_t);
    transpose_w<<<64, 256, 0, stream>>>(w1, Wt1);
    transpose_w<<<64, 256, 0, stream>>>(w2, Wt2);
    transpose_w<<<64, 256, 0, stream>>>(w3, Wt3);
    transpose_w<<<64, 256, 0, stream>>>(w4, Wt4);

    // K1: scatter-sum relu(X@W1^T+b1) into S_c (perm order)
    gemm128<true, true, true, false><<<N_BUILD / 128, 256, 0, stream>>>(
        x_building, Wt1, b1, perm_c, assign_bc, nullptr, S_c, N_BUILD);
    // K2: x_cable = (S_c/cnt)@W2^T + b2, in place
    gemm128<false, false, false, true><<<(N_CABLE + 127) / 128, 256, 0, stream>>>(
        S_c, Wt2, b2, nullptr, nullptr, cnt_c, S_c, N_CABLE);
    // K3: scatter-sum relu(x_cable@W3^T+b3) into S_t (perm order)
    gemm128<true, true, true, false><<<(N_CABLE + 127) / 128, 256, 0, stream>>>(
        S_c, Wt3, b3, perm_t, assign_ct, nullptr, S_t, N_CABLE);
    // K4: x_trans = (S_t/cnt)@W4^T + b4, in place
    gemm128<false, false, false, true><<<(N_TRANS + 127) / 128, 256, 0, stream>>>(
        S_t, Wt4, b4, nullptr, nullptr, cnt_t, S_t, N_TRANS);
}